// Round 5
// baseline (657.230 us; speedup 1.0000x reference)
//
#include <hip/hip_runtime.h>

// LightGCN: 3-layer propagation, 1.6M edges, D=128.
// R5: two-phase bucketed CSR build. R4's fill_k wrote 100MB (64B line per
// random 8B meta write). Now: fill1 scatters into (bucket,chunk)-ordered tmp
// with sequential XCD-local cursors (full-line writebacks, ~13MB), fill2
// finalizes per-bucket in an L2-local 32KB span and emits rs[] from LDS scan.
// Gathers (bf16 in/out, f32 accum) unchanged from R4.

static constexpr int USERS  = 50000;
static constexpr int NNODES = 100000;
static constexpr int DIM    = 128;
static constexpr int NEDGES = 1600000;
static constexpr long NELEM = (long)NNODES * DIM;   // 12.8M
static constexpr int NBUCK  = (NNODES + 255) / 256; // 391 buckets of 256 nodes
static constexpr int NCHUNK = 8;                    // pinned to XCDs via bid%8
static constexpr int CHUNK  = NEDGES / NCHUNK;      // 200000
static constexpr int NCNT   = NBUCK * NCHUNK;       // 3128 counters

__device__ __forceinline__ unsigned short f2bf(float f) {
    unsigned int u = __float_as_uint(f);
    unsigned int r = (u + 0x7FFFu + ((u >> 16) & 1)) >> 16;
    return (unsigned short)r;
}
__device__ __forceinline__ unsigned int pack2(float a, float b) {
    return (unsigned int)f2bf(a) | ((unsigned int)f2bf(b) << 16);
}
__device__ __forceinline__ float bflo(unsigned int p) { return __uint_as_float(p << 16); }
__device__ __forceinline__ float bfhi(unsigned int p) { return __uint_as_float(p & 0xFFFF0000u); }

// concat u/i embeds -> E0 (bf16 as uint pairs)
__global__ void init_k(const float* __restrict__ uE, const float* __restrict__ iE,
                       unsigned int* __restrict__ E0) {
    long base = ((long)blockIdx.x * blockDim.x + threadIdx.x) * 8;
    if (base >= NELEM) return;
    const long usplit = (long)USERS * DIM;
    const float* s = (base < usplit) ? (uE + base) : (iE + (base - usplit));
    float4 f0 = *(const float4*)(s);
    float4 f1 = *(const float4*)(s + 4);
    uint4 o;
    o.x = pack2(f0.x, f0.y); o.y = pack2(f0.z, f0.w);
    o.z = pack2(f1.x, f1.y); o.w = pack2(f1.z, f1.w);
    *(uint4*)(E0 + base / 2) = o;
}

// ---------- CSR build, two-phase ----------
// counters indexed [bucket*8 + chunk]
__global__ void histC_k(const int* __restrict__ edst, int* __restrict__ cnt) {
    int e = blockIdx.x * blockDim.x + threadIdx.x;
    if (e >= NEDGES) return;
    int b = edst[e] >> 8;
    int c = e / CHUNK;
    atomicAdd(&cnt[b * NCHUNK + c], 1);
}

// single-block exclusive scan over 3128 counters -> off (cursors) + bstart
__global__ void scanB_k(const int* __restrict__ cnt, int* __restrict__ off,
                        int* __restrict__ bstart, int* __restrict__ rs) {
    constexpr int PER = (NCNT + 255) / 256;        // 13
    __shared__ int sv[256 * PER];
    __shared__ int sp[256];
    int t = threadIdx.x;
    int base = t * PER;
    int sum = 0;
    #pragma unroll
    for (int k = 0; k < PER; ++k) {
        int idx = base + k;
        int v = (idx < NCNT) ? cnt[idx] : 0;
        sv[base + k] = sum;                        // thread-local exclusive
        sum += v;
    }
    sp[t] = sum;
    __syncthreads();
    // Hillis-Steele inclusive over 256 partials
    for (int o = 1; o < 256; o <<= 1) {
        int x = (t >= o) ? sp[t - o] : 0;
        __syncthreads();
        sp[t] += x;
        __syncthreads();
    }
    int pref = sp[t] - sum;                        // block-level exclusive
    #pragma unroll
    for (int k = 0; k < PER; ++k) {
        int idx = base + k;
        if (idx < NCNT) sv[base + k] += pref;
    }
    __syncthreads();
    #pragma unroll
    for (int k = 0; k < PER; ++k) {
        int idx = base + k;
        if (idx < NCNT) off[idx] = sv[idx];
    }
    for (int b = t; b < NBUCK; b += 256) bstart[b] = sv[b * NCHUNK];
    if (t == 0) { bstart[NBUCK] = NEDGES; rs[NNODES] = NEDGES; }
}

// scatter edges into (bucket,chunk)-ordered tmp; chunk pinned to XCD (bid%8)
__global__ void fill1_k(const int* __restrict__ esrc, const int* __restrict__ edst,
                        const float* __restrict__ eval,
                        int* __restrict__ off, int2* __restrict__ tmp) {
    int c = blockIdx.x & 7;                        // chunk == XCD (empirical)
    int j = blockIdx.x >> 3;                       // 0..97
    #pragma unroll
    for (int k = 0; k < 8; ++k) {
        int local = j * 2048 + k * 256 + threadIdx.x;
        if (local >= CHUNK) break;
        int e = c * CHUNK + local;
        int d = edst[e];
        int b = d >> 8;
        int p = atomicAdd(&off[b * NCHUNK + c], 1);
        tmp[p] = make_int2(esrc[e] | ((d & 255) << 17), __float_as_int(eval[e]));
    }
}

// per-bucket finalize: LDS count+scan -> rs[], then place into meta
__global__ void fill2_k(const int2* __restrict__ tmp, const int* __restrict__ bstart,
                        int* __restrict__ rs, int2* __restrict__ meta) {
    __shared__ int cnt[256];
    __shared__ int pos[256];
    int b = blockIdx.x;
    int t = threadIdx.x;
    int beg = bstart[b], end = bstart[b + 1];
    cnt[t] = 0;
    __syncthreads();
    for (int i = beg + t; i < end; i += 256)
        atomicAdd(&cnt[(tmp[i].x >> 17) & 255], 1);
    __syncthreads();
    int v = cnt[t];
    pos[t] = v;
    __syncthreads();
    for (int o = 1; o < 256; o <<= 1) {
        int x = (t >= o) ? pos[t - o] : 0;
        __syncthreads();
        pos[t] += x;
        __syncthreads();
    }
    int start = pos[t] - v + beg;                  // exclusive + bucket base
    int node = b * 256 + t;
    if (node < NNODES) rs[node] = start;
    __syncthreads();
    pos[t] = start;                                // becomes cursor
    __syncthreads();
    for (int i = beg + t; i < end; i += 256) {
        int2 m = tmp[i];
        int n = (m.x >> 17) & 255;
        int slot = atomicAdd(&pos[n], 1);
        meta[slot] = make_int2(m.x & 0x1FFFF, m.y);
    }
}

// ---------- gather: 1 wave/dest row; bf16 in/out; f32 accum ----------
__global__ void gather_k(const int* __restrict__ rs, const int2* __restrict__ meta,
                         const unsigned int* __restrict__ cur,
                         unsigned int* __restrict__ nxt) {
    int row = blockIdx.x * (blockDim.x >> 6) + (threadIdx.x >> 6);
    if (row >= NNODES) return;
    int lane = threadIdx.x & 63;
    int beg = rs[row], end = rs[row + 1];
    float sx = 0.f, sy = 0.f, tx = 0.f, ty = 0.f;
    int i = beg;
    for (; i + 1 < end; i += 2) {
        int2 m0 = meta[i];
        int2 m1 = meta[i + 1];
        unsigned int p0 = cur[(long)m0.x * 64 + lane];
        unsigned int p1 = cur[(long)m1.x * 64 + lane];
        float v0 = __int_as_float(m0.y);
        float v1 = __int_as_float(m1.y);
        sx += bflo(p0) * v0;  sy += bfhi(p0) * v0;
        tx += bflo(p1) * v1;  ty += bfhi(p1) * v1;
    }
    if (i < end) {
        int2 m = meta[i];
        unsigned int p = cur[(long)m.x * 64 + lane];
        float v = __int_as_float(m.y);
        sx += bflo(p) * v;  sy += bfhi(p) * v;
    }
    nxt[(long)row * 64 + lane] = pack2(sx + tx, sy + ty);
}

// ---------- final: out = embeds(f32) + L1 + L2 + L3 ----------
__global__ void final_k(const float* __restrict__ uE, const float* __restrict__ iE,
                        const unsigned int* __restrict__ L1,
                        const unsigned int* __restrict__ L2,
                        const unsigned int* __restrict__ L3,
                        float* __restrict__ out) {
    long base = ((long)blockIdx.x * blockDim.x + threadIdx.x) * 8;
    if (base >= NELEM) return;
    const long usplit = (long)USERS * DIM;
    const float* s = (base < usplit) ? (uE + base) : (iE + (base - usplit));
    float4 a = *(const float4*)(s);
    float4 b = *(const float4*)(s + 4);
    uint4 l1 = *(const uint4*)(L1 + base / 2);
    uint4 l2 = *(const uint4*)(L2 + base / 2);
    uint4 l3 = *(const uint4*)(L3 + base / 2);
    a.x += bflo(l1.x) + bflo(l2.x) + bflo(l3.x);
    a.y += bfhi(l1.x) + bfhi(l2.x) + bfhi(l3.x);
    a.z += bflo(l1.y) + bflo(l2.y) + bflo(l3.y);
    a.w += bfhi(l1.y) + bfhi(l2.y) + bfhi(l3.y);
    b.x += bflo(l1.z) + bflo(l2.z) + bflo(l3.z);
    b.y += bfhi(l1.z) + bfhi(l2.z) + bfhi(l3.z);
    b.z += bflo(l1.w) + bflo(l2.w) + bflo(l3.w);
    b.w += bfhi(l1.w) + bfhi(l2.w) + bfhi(l3.w);
    *(float4*)(out + base)     = a;
    *(float4*)(out + base + 4) = b;
}

// ---------- fallback: R2 atomic path ----------
__global__ void init_f32_k(const float* __restrict__ uE, const float* __restrict__ iE,
                           float* __restrict__ acc, float* __restrict__ cur) {
    long base = ((long)blockIdx.x * blockDim.x + threadIdx.x) * 8;
    if (base >= NELEM) return;
    const long usplit = (long)USERS * DIM;
    const float* s = (base < usplit) ? (uE + base) : (iE + (base - usplit));
    float4 f0 = *(const float4*)(s);
    float4 f1 = *(const float4*)(s + 4);
    *(float4*)(acc + base)     = f0;
    *(float4*)(acc + base + 4) = f1;
    *(float4*)(cur + base)     = f0;
    *(float4*)(cur + base + 4) = f1;
}
__global__ void scatter_k(const int* __restrict__ esrc, const int* __restrict__ edst,
                          const float* __restrict__ eval,
                          const float* __restrict__ cur, float* __restrict__ nxt) {
    long g = (long)blockIdx.x * blockDim.x + threadIdx.x;
    if (g >= (long)NEDGES * 32) return;
    int e  = (int)(g >> 5);
    int d0 = ((int)g & 31) * 4;
    float v = eval[e];
    float4 x = *(const float4*)(cur + (long)esrc[e] * DIM + d0);
    float* o = nxt + (long)edst[e] * DIM + d0;
    unsafeAtomicAdd(o + 0, x.x * v);
    unsafeAtomicAdd(o + 1, x.y * v);
    unsafeAtomicAdd(o + 2, x.z * v);
    unsafeAtomicAdd(o + 3, x.w * v);
}
__global__ void add_k(float* __restrict__ acc, const float* __restrict__ nxt) {
    long g = ((long)blockIdx.x * blockDim.x + threadIdx.x) * 4;
    if (g >= NELEM) return;
    float4 a = *(const float4*)(acc + g);
    float4 n = *(const float4*)(nxt + g);
    a.x += n.x; a.y += n.y; a.z += n.z; a.w += n.w;
    *(float4*)(acc + g) = a;
}

extern "C" void kernel_launch(void* const* d_in, const int* in_sizes, int n_in,
                              void* d_out, int out_size, void* d_ws, size_t ws_size,
                              hipStream_t stream) {
    const float* uE   = (const float*)d_in[0];
    const float* iE   = (const float*)d_in[1];
    const int*   esrc = (const int*)d_in[2];
    const int*   edst = (const int*)d_in[3];
    const float* eval = (const float*)d_in[4];
    float* out = (float*)d_out;

    char* ws = (char*)d_ws;
    const long NU = NELEM / 2;                      // uints per layer buffer
    unsigned int* E0 = (unsigned int*)ws;           // 25.6 MB
    unsigned int* L1 = E0 + NU;                     // 25.6 MB
    unsigned int* L2 = L1 + NU;                     // 25.6 MB
    unsigned int* L3 = L2 + NU;                     // 25.6 MB
    int2* meta   = (int2*)(L3 + NU);                // 12.8 MB
    int2* tmp    = (int2*)L3;                       // aliases L3 (free until last gather)
    int*  rs     = (int*)(meta + NEDGES);           // NNODES+1
    int*  off    = rs + NNODES + 1;                 // 3128 cursors
    int*  bstart = off + NCNT;                      // NBUCK+1
    size_t need  = (size_t)((char*)(bstart + NBUCK + 1) - ws);

    if (ws_size >= need) {
        init_k<<<(int)((NELEM / 8 + 255) / 256), 256, 0, stream>>>(uE, iE, E0);

        hipMemsetAsync(off, 0, (size_t)NCNT * sizeof(int), stream);
        histC_k<<<(NEDGES + 255) / 256, 256, 0, stream>>>(edst, off);   // off = counts
        // scan reads counts from off's memory? No: scan needs counts separate from
        // cursor output. Use bstart-adjacent scratch? Simpler: scan in-place is fine
        // because scanB reads all cnt before writing off — but they alias. Read into
        // registers first: scanB loads cnt[idx] then writes off[idx]; with cnt==off
        // each thread reads its own slots before writing them, and no cross-thread
        // RAW exists (each idx read+written by same thread, write after full read
        // loop). Safe.
        scanB_k<<<1, 256, 0, stream>>>(off, off, bstart, rs);
        fill1_k<<<8 * ((CHUNK + 2047) / 2048), 256, 0, stream>>>(esrc, edst, eval, off, tmp);
        fill2_k<<<NBUCK, 256, 0, stream>>>(tmp, bstart, rs, meta);

        const int gblocks = (NNODES * 64 + 255) / 256;
        gather_k<<<gblocks, 256, 0, stream>>>(rs, meta, E0, L1);
        gather_k<<<gblocks, 256, 0, stream>>>(rs, meta, L1, L2);
        gather_k<<<gblocks, 256, 0, stream>>>(rs, meta, L2, L3);

        final_k<<<(int)((NELEM / 8 + 255) / 256), 256, 0, stream>>>(uE, iE, L1, L2, L3, out);
    } else {
        float* bufA = (float*)ws;
        float* bufB = bufA + NELEM;
        const size_t SZ = (size_t)NELEM * sizeof(float);
        init_f32_k<<<(int)((NELEM / 8 + 255) / 256), 256, 0, stream>>>(uE, iE, out, bufA);
        float* cur = bufA;
        float* nxt = bufB;
        for (int l = 0; l < 3; ++l) {
            hipMemsetAsync(nxt, 0, SZ, stream);
            long nthreads = (long)NEDGES * 32;
            scatter_k<<<(int)((nthreads + 255) / 256), 256, 0, stream>>>(esrc, edst, eval, cur, nxt);
            add_k<<<(int)((NELEM / 4 + 255) / 256), 256, 0, stream>>>(out, nxt);
            float* t = cur; cur = nxt; nxt = t;
        }
    }
}

// Round 6
// 438.497 us; speedup vs baseline: 1.4988x; 1.4988x over previous
//
#include <hip/hip_runtime.h>

// LightGCN: 3-layer propagation, 1.6M edges, D=128.
// R6: zero-global-atomic CSR build. R5 lesson: scatter cost = distinct dirty
// lines; only dense WG-local staging fixes it. part_k bins 8192 edges/WG into
// 391 dst-buckets via LDS (hist+scan+stage), flushes sequentially to a
// WG-private tmp region. fill2_k per bucket: segmented read, LDS node
// count+scan -> rs[], dense placement into meta. Gathers/final = R4 proven.

static constexpr int USERS  = 50000;
static constexpr int NNODES = 100000;
static constexpr int DIM    = 128;
static constexpr int NEDGES = 1600000;
static constexpr long NELEM = (long)NNODES * DIM;     // 12.8M
static constexpr int NBK    = (NNODES + 255) / 256;   // 391 buckets x 256 nodes
static constexpr int EPW    = 8192;                   // edges per partition WG
static constexpr int NWG    = (NEDGES + EPW - 1) / EPW; // 196
static constexpr int SSROW  = NBK + 1;                // 392

__device__ __forceinline__ unsigned short f2bf(float f) {
    unsigned int u = __float_as_uint(f);
    unsigned int r = (u + 0x7FFFu + ((u >> 16) & 1)) >> 16;
    return (unsigned short)r;
}
__device__ __forceinline__ unsigned int pack2(float a, float b) {
    return (unsigned int)f2bf(a) | ((unsigned int)f2bf(b) << 16);
}
__device__ __forceinline__ float bflo(unsigned int p) { return __uint_as_float(p << 16); }
__device__ __forceinline__ float bfhi(unsigned int p) { return __uint_as_float(p & 0xFFFF0000u); }

// concat u/i embeds -> E0 (bf16 as uint pairs)
__global__ void init_k(const float* __restrict__ uE, const float* __restrict__ iE,
                       unsigned int* __restrict__ E0) {
    long base = ((long)blockIdx.x * blockDim.x + threadIdx.x) * 8;
    if (base >= NELEM) return;
    const long usplit = (long)USERS * DIM;
    const float* s = (base < usplit) ? (uE + base) : (iE + (base - usplit));
    float4 f0 = *(const float4*)(s);
    float4 f1 = *(const float4*)(s + 4);
    uint4 o;
    o.x = pack2(f0.x, f0.y); o.y = pack2(f0.z, f0.w);
    o.z = pack2(f1.x, f1.y); o.w = pack2(f1.z, f1.w);
    *(uint4*)(E0 + base / 2) = o;
}

// ---------- partition: LDS-staged bucket binning, sequential flush ----------
__global__ void part_k(const int* __restrict__ esrc, const int* __restrict__ edst,
                       const float* __restrict__ eval,
                       int* __restrict__ ssP, int2* __restrict__ tmp) {
    __shared__ int2 stage[EPW];            // 64 KB
    __shared__ int hist[NBK];
    __shared__ int cursor[NBK];
    __shared__ int sp[256];
    int w = blockIdx.x, t = threadIdx.x;
    int ebase = w * EPW;
    int n = NEDGES - ebase; if (n > EPW) n = EPW;

    for (int b = t; b < NBK; b += 256) hist[b] = 0;
    __syncthreads();
    #pragma unroll
    for (int k = 0; k < EPW / 256; ++k) {
        int idx = k * 256 + t;
        if (idx < n) atomicAdd(&hist[edst[ebase + idx] >> 8], 1);
    }
    __syncthreads();
    // exclusive scan hist -> cursor (2 slots per thread)
    int b0 = 2 * t, b1 = 2 * t + 1;
    int v0 = (b0 < NBK) ? hist[b0] : 0;
    int v1 = (b1 < NBK) ? hist[b1] : 0;
    int psum = v0 + v1;
    sp[t] = psum;
    __syncthreads();
    for (int o = 1; o < 256; o <<= 1) {
        int x = (t >= o) ? sp[t - o] : 0;
        __syncthreads();
        sp[t] += x;
        __syncthreads();
    }
    int pref = sp[t] - psum;
    if (b0 < NBK) cursor[b0] = pref;
    if (b1 < NBK) cursor[b1] = pref + v0;
    __syncthreads();
    // export pristine segment starts + row total
    for (int b = t; b < NBK; b += 256) ssP[w * SSROW + b] = cursor[b];
    if (t == 0) ssP[w * SSROW + NBK] = n;
    __syncthreads();
    // place into LDS stage
    #pragma unroll
    for (int k = 0; k < EPW / 256; ++k) {
        int idx = k * 256 + t;
        if (idx < n) {
            int e = ebase + idx;
            int d = edst[e];
            int p = atomicAdd(&cursor[d >> 8], 1);
            stage[p] = make_int2(esrc[e] | ((d & 255) << 17), __float_as_int(eval[e]));
        }
    }
    __syncthreads();
    // flush sequentially
    #pragma unroll
    for (int k = 0; k < EPW / 256; ++k) {
        int idx = k * 256 + t;
        if (idx < n) tmp[ebase + idx] = stage[idx];
    }
}

// bucket bases from the segment table (one block)
__global__ void scanT_k(const int* __restrict__ ssP, int* __restrict__ bstart,
                        int* __restrict__ rs) {
    __shared__ int sp[1024];
    int t = threadIdx.x;
    int tot = 0;
    if (t < NBK) {
        for (int w = 0; w < NWG; ++w)
            tot += ssP[w * SSROW + t + 1] - ssP[w * SSROW + t];
    }
    sp[t] = tot;
    __syncthreads();
    for (int o = 1; o < 1024; o <<= 1) {
        int x = (t >= o) ? sp[t - o] : 0;
        __syncthreads();
        sp[t] += x;
        __syncthreads();
    }
    if (t < NBK) bstart[t] = sp[t] - tot;
    if (t == 0) { bstart[NBK] = NEDGES; rs[NNODES] = NEDGES; }
}

// per-bucket finalize: segmented read, LDS node count+scan -> rs, dense meta
__global__ void fill2_k(const int2* __restrict__ tmp, const int* __restrict__ ssP,
                        const int* __restrict__ bstart,
                        int* __restrict__ rs, int2* __restrict__ meta) {
    __shared__ int cnt[256];
    __shared__ int cur[256];
    __shared__ int sp2[256];
    int b = blockIdx.x, t = threadIdx.x;
    int base = bstart[b];
    int v = t >> 6, lane = t & 63;
    cnt[t] = 0;
    __syncthreads();
    for (int w = v; w < NWG; w += 4) {
        int s = ssP[w * SSROW + b];
        int e = ssP[w * SSROW + b + 1];
        const int2* seg = tmp + (long)w * EPW + s;
        for (int i = lane; i < e - s; i += 64)
            atomicAdd(&cnt[(seg[i].x >> 17) & 255], 1);
    }
    __syncthreads();
    int myc = cnt[t];
    sp2[t] = myc;
    __syncthreads();
    for (int o = 1; o < 256; o <<= 1) {
        int x = (t >= o) ? sp2[t - o] : 0;
        __syncthreads();
        sp2[t] += x;
        __syncthreads();
    }
    int start = base + sp2[t] - myc;
    int node = b * 256 + t;
    if (node < NNODES) rs[node] = start;
    cur[t] = start;
    __syncthreads();
    for (int w = v; w < NWG; w += 4) {
        int s = ssP[w * SSROW + b];
        int e = ssP[w * SSROW + b + 1];
        const int2* seg = tmp + (long)w * EPW + s;
        for (int i = lane; i < e - s; i += 64) {
            int2 m = seg[i];
            int slot = atomicAdd(&cur[(m.x >> 17) & 255], 1);
            meta[slot] = make_int2(m.x & 0x1FFFF, m.y);
        }
    }
}

// ---------- gather: 1 wave/dest row; bf16 in/out; f32 accum (R4 proven) ----------
__global__ void gather_k(const int* __restrict__ rs, const int2* __restrict__ meta,
                         const unsigned int* __restrict__ cur,
                         unsigned int* __restrict__ nxt) {
    int row = blockIdx.x * (blockDim.x >> 6) + (threadIdx.x >> 6);
    if (row >= NNODES) return;
    int lane = threadIdx.x & 63;
    int beg = rs[row], end = rs[row + 1];
    float sx = 0.f, sy = 0.f, tx = 0.f, ty = 0.f;
    int i = beg;
    for (; i + 1 < end; i += 2) {
        int2 m0 = meta[i];
        int2 m1 = meta[i + 1];
        unsigned int p0 = cur[(long)m0.x * 64 + lane];
        unsigned int p1 = cur[(long)m1.x * 64 + lane];
        float v0 = __int_as_float(m0.y);
        float v1 = __int_as_float(m1.y);
        sx += bflo(p0) * v0;  sy += bfhi(p0) * v0;
        tx += bflo(p1) * v1;  ty += bfhi(p1) * v1;
    }
    if (i < end) {
        int2 m = meta[i];
        unsigned int p = cur[(long)m.x * 64 + lane];
        float v = __int_as_float(m.y);
        sx += bflo(p) * v;  sy += bfhi(p) * v;
    }
    nxt[(long)row * 64 + lane] = pack2(sx + tx, sy + ty);
}

// ---------- final: out = embeds(f32) + L1 + L2 + L3 ----------
__global__ void final_k(const float* __restrict__ uE, const float* __restrict__ iE,
                        const unsigned int* __restrict__ L1,
                        const unsigned int* __restrict__ L2,
                        const unsigned int* __restrict__ L3,
                        float* __restrict__ out) {
    long base = ((long)blockIdx.x * blockDim.x + threadIdx.x) * 8;
    if (base >= NELEM) return;
    const long usplit = (long)USERS * DIM;
    const float* s = (base < usplit) ? (uE + base) : (iE + (base - usplit));
    float4 a = *(const float4*)(s);
    float4 b = *(const float4*)(s + 4);
    uint4 l1 = *(const uint4*)(L1 + base / 2);
    uint4 l2 = *(const uint4*)(L2 + base / 2);
    uint4 l3 = *(const uint4*)(L3 + base / 2);
    a.x += bflo(l1.x) + bflo(l2.x) + bflo(l3.x);
    a.y += bfhi(l1.x) + bfhi(l2.x) + bfhi(l3.x);
    a.z += bflo(l1.y) + bflo(l2.y) + bflo(l3.y);
    a.w += bfhi(l1.y) + bfhi(l2.y) + bfhi(l3.y);
    b.x += bflo(l1.z) + bflo(l2.z) + bflo(l3.z);
    b.y += bfhi(l1.z) + bfhi(l2.z) + bfhi(l3.z);
    b.z += bflo(l1.w) + bflo(l2.w) + bflo(l3.w);
    b.w += bfhi(l1.w) + bfhi(l2.w) + bfhi(l3.w);
    *(float4*)(out + base)     = a;
    *(float4*)(out + base + 4) = b;
}

// ---------- fallback: R2 atomic path ----------
__global__ void init_f32_k(const float* __restrict__ uE, const float* __restrict__ iE,
                           float* __restrict__ acc, float* __restrict__ cur) {
    long base = ((long)blockIdx.x * blockDim.x + threadIdx.x) * 8;
    if (base >= NELEM) return;
    const long usplit = (long)USERS * DIM;
    const float* s = (base < usplit) ? (uE + base) : (iE + (base - usplit));
    float4 f0 = *(const float4*)(s);
    float4 f1 = *(const float4*)(s + 4);
    *(float4*)(acc + base)     = f0;
    *(float4*)(acc + base + 4) = f1;
    *(float4*)(cur + base)     = f0;
    *(float4*)(cur + base + 4) = f1;
}
__global__ void scatter_k(const int* __restrict__ esrc, const int* __restrict__ edst,
                          const float* __restrict__ eval,
                          const float* __restrict__ cur, float* __restrict__ nxt) {
    long g = (long)blockIdx.x * blockDim.x + threadIdx.x;
    if (g >= (long)NEDGES * 32) return;
    int e  = (int)(g >> 5);
    int d0 = ((int)g & 31) * 4;
    float v = eval[e];
    float4 x = *(const float4*)(cur + (long)esrc[e] * DIM + d0);
    float* o = nxt + (long)edst[e] * DIM + d0;
    unsafeAtomicAdd(o + 0, x.x * v);
    unsafeAtomicAdd(o + 1, x.y * v);
    unsafeAtomicAdd(o + 2, x.z * v);
    unsafeAtomicAdd(o + 3, x.w * v);
}
__global__ void add_k(float* __restrict__ acc, const float* __restrict__ nxt) {
    long g = ((long)blockIdx.x * blockDim.x + threadIdx.x) * 4;
    if (g >= NELEM) return;
    float4 a = *(const float4*)(acc + g);
    float4 n = *(const float4*)(nxt + g);
    a.x += n.x; a.y += n.y; a.z += n.z; a.w += n.w;
    *(float4*)(acc + g) = a;
}

extern "C" void kernel_launch(void* const* d_in, const int* in_sizes, int n_in,
                              void* d_out, int out_size, void* d_ws, size_t ws_size,
                              hipStream_t stream) {
    const float* uE   = (const float*)d_in[0];
    const float* iE   = (const float*)d_in[1];
    const int*   esrc = (const int*)d_in[2];
    const int*   edst = (const int*)d_in[3];
    const float* eval = (const float*)d_in[4];
    float* out = (float*)d_out;

    char* ws = (char*)d_ws;
    const long NU = NELEM / 2;                      // uints per layer buffer
    unsigned int* E0 = (unsigned int*)ws;           // 25.6 MB
    unsigned int* L1 = E0 + NU;                     // 25.6 MB
    unsigned int* L2 = L1 + NU;                     // 25.6 MB
    unsigned int* L3 = L2 + NU;                     // 25.6 MB
    int2* meta   = (int2*)(L3 + NU);                // 12.8 MB
    int*  rs     = (int*)(meta + NEDGES);           // NNODES+1
    int*  bstart = rs + NNODES + 1;                 // NBK+1
    size_t need  = (size_t)((char*)(bstart + NBK + 1) - ws);
    // aliases (dead before their host buffer is written):
    int2* tmp = (int2*)L2;                          // consumed by fill2 (pre-gather2)
    int*  ssP = (int*)L3;                           // consumed by fill2 (pre-gather3)

    if (ws_size >= need) {
        init_k<<<(int)((NELEM / 8 + 255) / 256), 256, 0, stream>>>(uE, iE, E0);

        part_k<<<NWG, 256, 0, stream>>>(esrc, edst, eval, ssP, tmp);
        scanT_k<<<1, 1024, 0, stream>>>(ssP, bstart, rs);
        fill2_k<<<NBK, 256, 0, stream>>>(tmp, ssP, bstart, rs, meta);

        const int gblocks = (NNODES * 64 + 255) / 256;
        gather_k<<<gblocks, 256, 0, stream>>>(rs, meta, E0, L1);
        gather_k<<<gblocks, 256, 0, stream>>>(rs, meta, L1, L2);
        gather_k<<<gblocks, 256, 0, stream>>>(rs, meta, L2, L3);

        final_k<<<(int)((NELEM / 8 + 255) / 256), 256, 0, stream>>>(uE, iE, L1, L2, L3, out);
    } else {
        float* bufA = (float*)ws;
        float* bufB = bufA + NELEM;
        const size_t SZ = (size_t)NELEM * sizeof(float);
        init_f32_k<<<(int)((NELEM / 8 + 255) / 256), 256, 0, stream>>>(uE, iE, out, bufA);
        float* cur = bufA;
        float* nxt = bufB;
        for (int l = 0; l < 3; ++l) {
            hipMemsetAsync(nxt, 0, SZ, stream);
            long nthreads = (long)NEDGES * 32;
            scatter_k<<<(int)((nthreads + 255) / 256), 256, 0, stream>>>(esrc, edst, eval, cur, nxt);
            add_k<<<(int)((NELEM / 4 + 255) / 256), 256, 0, stream>>>(out, nxt);
            float* t = cur; cur = nxt; nxt = t;
        }
    }
}